// Round 6
// baseline (205.836 us; speedup 1.0000x reference)
//
#include <hip/hip_runtime.h>

// HighOrderActivationB, round 5: 4 tasks/thread for MLP (compile-fixed NT stores).
//   Per task: stable-sort |a| (asc), coef = diffs, ternary suffix-sum index,
//   out[d] = sum_j coef[j]*params[g, idx[j], d].
// X loads: 3x float4 per thread (48B aligned). Stores: 8x float4 nontemporal.

#define B_BATCH 4096
#define N_GROUPS 1024
#define N_TERMS 27
#define OUT_DIM 8
#define TPT 4   // tasks per thread

typedef float floatx4 __attribute__((ext_vector_type(4)));

__global__ __launch_bounds__(256)
void hoa_kernel(const float* __restrict__ X,
                const float* __restrict__ P,
                float* __restrict__ out) {
    const int t = blockIdx.x * blockDim.x + threadIdx.x;
    const int base = t * TPT;                       // first task = b*N_GROUPS + g

    // ---- 12 contiguous floats = 3 aligned float4 loads ----
    const floatx4* xp = (const floatx4*)(X + (size_t)base * 3);
    const floatx4 x0 = xp[0];
    const floatx4 x1 = xp[1];
    const floatx4 x2 = xp[2];
    const float a[12] = { x0.x, x0.y, x0.z, x0.w,
                          x1.x, x1.y, x1.z, x1.w,
                          x2.x, x2.y, x2.z, x2.w };

    floatx4 o[2 * TPT];

    #pragma unroll
    for (int k = 0; k < TPT; ++k) {
        const float A0 = a[3 * k + 0];
        const float A1 = a[3 * k + 1];
        const float A2 = a[3 * k + 2];

        float m0 = fabsf(A0), m1 = fabsf(A1), m2 = fabsf(A2);
        int t0 = (A0 >= 0.0f) ? 1 : -1;
        int t1 = (A1 >= 0.0f) ? 3 : -3;
        int t2 = (A2 >= 0.0f) ? 9 : -9;

        // stable ascending 3-sort by magnitude (strict > = stable)
        if (m0 > m1) { float tm = m0; m0 = m1; m1 = tm; int tt = t0; t0 = t1; t1 = tt; }
        if (m1 > m2) { float tm = m1; m1 = m2; m2 = tm; int tt = t1; t1 = t2; t2 = tt; }
        if (m0 > m1) { float tm = m0; m0 = m1; m1 = tm; int tt = t0; t0 = t1; t1 = tt; }

        const float c0 = m0;
        const float c1 = m1 - m0;
        const float c2 = m2 - m1;

        const int i2 = 13 + t2;
        const int i1 = i2 + t1;
        const int i0 = i1 + t0;

        const int g = (base + k) & (N_GROUPS - 1);
        const float* pg = P + (size_t)g * (N_TERMS * OUT_DIM);
        const floatx4* r0 = (const floatx4*)(pg + i0 * OUT_DIM);
        const floatx4* r1 = (const floatx4*)(pg + i1 * OUT_DIM);
        const floatx4* r2 = (const floatx4*)(pg + i2 * OUT_DIM);
        const floatx4 g0a = r0[0], g0b = r0[1];
        const floatx4 g1a = r1[0], g1b = r1[1];
        const floatx4 g2a = r2[0], g2b = r2[1];

        o[2 * k + 0] = c0 * g0a + c1 * g1a + c2 * g2a;
        o[2 * k + 1] = c0 * g0b + c1 * g1b + c2 * g2b;
    }

    // ---- 8x float4 nontemporal stores (write-only data; skip cache) ----
    floatx4* op = (floatx4*)(out + (size_t)base * OUT_DIM);
    #pragma unroll
    for (int i = 0; i < 2 * TPT; ++i) {
        __builtin_nontemporal_store(o[i], op + i);
    }
}

extern "C" void kernel_launch(void* const* d_in, const int* in_sizes, int n_in,
                              void* d_out, int out_size, void* d_ws, size_t ws_size,
                              hipStream_t stream) {
    const float* X = (const float*)d_in[0];
    const float* P = (const float*)d_in[1];
    float* out = (float*)d_out;

    const int total_tasks = B_BATCH * N_GROUPS;     // 4,194,304
    const int threads = total_tasks / TPT;          // 1,048,576
    const int block = 256;
    const int grid = threads / block;               // 4096 blocks
    hoa_kernel<<<grid, block, 0, stream>>>(X, P, out);
}

// Round 7
// 67.540 us; speedup vs baseline: 3.0476x; 3.0476x over previous
//
#include <hip/hip_runtime.h>

// HighOrderActivationB, round 6: 4 tasks/thread, WAVE-INTERLEAVED (stride 256).
// Every memory instruction keeps the baseline's per-inst lane geometry
// (dense 12B-stride X loads, 32B-stride float4 stores -> L2 merges to exact
// 134MB), but 4x memory ops in flight per wave (latency-bound fix).
// NO nontemporal stores (round-5 lesson: NT + strided = 3.3x write amp).

#define B_BATCH 4096
#define N_GROUPS 1024
#define N_TERMS 27
#define OUT_DIM 8
#define TPT 4   // tasks per thread, strided by blockDim

__global__ __launch_bounds__(256)
void hoa_kernel(const float* __restrict__ X,
                const float* __restrict__ P,
                float* __restrict__ out) {
    const int t0 = blockIdx.x * (256 * TPT) + threadIdx.x;  // first task of this thread

    // ---- issue all X loads up front: 12 dword loads in flight ----
    float a[3 * TPT];
    #pragma unroll
    for (int k = 0; k < TPT; ++k) {
        const float* xp = X + (size_t)(t0 + k * 256) * 3;
        a[3 * k + 0] = xp[0];
        a[3 * k + 1] = xp[1];
        a[3 * k + 2] = xp[2];
    }

    #pragma unroll
    for (int k = 0; k < TPT; ++k) {
        const int task = t0 + k * 256;
        const float A0 = a[3 * k + 0];
        const float A1 = a[3 * k + 1];
        const float A2 = a[3 * k + 2];

        float m0 = fabsf(A0), m1 = fabsf(A1), m2 = fabsf(A2);
        int t0i = (A0 >= 0.0f) ? 1 : -1;
        int t1i = (A1 >= 0.0f) ? 3 : -3;
        int t2i = (A2 >= 0.0f) ? 9 : -9;

        // stable ascending 3-sort by magnitude (strict > = stable)
        if (m0 > m1) { float tm = m0; m0 = m1; m1 = tm; int tt = t0i; t0i = t1i; t1i = tt; }
        if (m1 > m2) { float tm = m1; m1 = m2; m2 = tm; int tt = t1i; t1i = t2i; t2i = tt; }
        if (m0 > m1) { float tm = m0; m0 = m1; m1 = tm; int tt = t0i; t0i = t1i; t1i = tt; }

        const float c0 = m0;
        const float c1 = m1 - m0;
        const float c2 = m2 - m1;

        const int i2 = 13 + t2i;
        const int i1 = i2 + t1i;
        const int i0 = i1 + t0i;

        const int g = task & (N_GROUPS - 1);
        const float* pg = P + (size_t)g * (N_TERMS * OUT_DIM);
        const float4* r0 = (const float4*)(pg + i0 * OUT_DIM);
        const float4* r1 = (const float4*)(pg + i1 * OUT_DIM);
        const float4* r2 = (const float4*)(pg + i2 * OUT_DIM);
        const float4 g0a = r0[0], g0b = r0[1];
        const float4 g1a = r1[0], g1b = r1[1];
        const float4 g2a = r2[0], g2b = r2[1];

        float4 oa, ob;
        oa.x = c0 * g0a.x + c1 * g1a.x + c2 * g2a.x;
        oa.y = c0 * g0a.y + c1 * g1a.y + c2 * g2a.y;
        oa.z = c0 * g0a.z + c1 * g1a.z + c2 * g2a.z;
        oa.w = c0 * g0a.w + c1 * g1a.w + c2 * g2a.w;
        ob.x = c0 * g0b.x + c1 * g1b.x + c2 * g2b.x;
        ob.y = c0 * g0b.y + c1 * g1b.y + c2 * g2b.y;
        ob.z = c0 * g0b.z + c1 * g1b.z + c2 * g2b.z;
        ob.w = c0 * g0b.w + c1 * g1b.w + c2 * g2b.w;

        // regular cached stores: 32B lane stride, L2 merges to full lines
        float4* op = (float4*)(out + (size_t)task * OUT_DIM);
        op[0] = oa;
        op[1] = ob;
    }
}

extern "C" void kernel_launch(void* const* d_in, const int* in_sizes, int n_in,
                              void* d_out, int out_size, void* d_ws, size_t ws_size,
                              hipStream_t stream) {
    const float* X = (const float*)d_in[0];
    const float* P = (const float*)d_in[1];
    float* out = (float*)d_out;

    const int total_tasks = B_BATCH * N_GROUPS;       // 4,194,304
    const int block = 256;
    const int grid = total_tasks / (block * TPT);     // 4096 blocks
    hoa_kernel<<<grid, block, 0, stream>>>(X, P, out);
}

// Round 9
// 36.438 us; speedup vs baseline: 5.6489x; 1.8536x over previous
//
#include <hip/hip_runtime.h>

// HighOrderActivationB, round 7: LDS-staged param gathers.
// Diagnosis: param gathers are 64-way address-divergent per instruction
// (consecutive lanes -> consecutive g -> tables 864B apart) => ~64 L1 line
// transactions per gather instr; TA pipe saturated (round 6: 4x MLP = null).
// Fix: block owns 32 groups x 128 batch rows; stage 32x216 floats (27 KB)
// in LDS, gather from LDS pipe instead. X loads & out stores keep dense
// lane geometry; WRITE_SIZE must stay exactly 134 MB.

#define B_BATCH 4096
#define N_GROUPS 1024
#define N_TERMS 27
#define OUT_DIM 8
#define GC 32           // groups per block
#define BC 128          // batch rows per block
#define ROW_STRIDE 228  // dwords per group row in LDS: %32==4 (bank spread), *4%16==0 (b128 aligned)

typedef float floatx4 __attribute__((ext_vector_type(4)));

__global__ __launch_bounds__(256)
void hoa_kernel(const float* __restrict__ X,
                const float* __restrict__ P,
                float* __restrict__ out) {
    __shared__ float lds[GC * ROW_STRIDE];   // 29184 B

    const int tid = threadIdx.x;
    const int g0 = blockIdx.x * GC;
    const int b0 = blockIdx.y * BC;

    // ---- stage params for GC groups: 32 rows x 54 float4 ----
    {
        const floatx4* P4 = (const floatx4*)(P + (size_t)g0 * (N_TERMS * OUT_DIM));
        floatx4* L4 = (floatx4*)lds;
        for (int i = tid; i < GC * 54; i += 256) {
            const int r = i / 54;
            const int c = i - r * 54;
            L4[r * 57 + c] = P4[i];        // lds row = 57 float4 (228 dwords)
        }
    }
    __syncthreads();

    const int g_local = tid & (GC - 1);
    const int b_slot = tid >> 5;             // 0..7
    const float* lg = lds + g_local * ROW_STRIDE;
    const int g = g0 + g_local;

    for (int it = 0; it < BC / 8; ++it) {
        const int b = b0 + b_slot + it * 8;

        // dense X read: wave lanes = 32 consecutive g x 2 b -> 2 x 384B segments
        const float* xp = X + (size_t)b * (N_GROUPS * 3) + g * 3;
        const float A0 = xp[0];
        const float A1 = xp[1];
        const float A2 = xp[2];

        float m0 = fabsf(A0), m1 = fabsf(A1), m2 = fabsf(A2);
        int t0 = (A0 >= 0.0f) ? 1 : -1;
        int t1 = (A1 >= 0.0f) ? 3 : -3;
        int t2 = (A2 >= 0.0f) ? 9 : -9;

        // stable ascending 3-sort by magnitude (strict > = stable)
        if (m0 > m1) { float tm=m0; m0=m1; m1=tm; int tt=t0; t0=t1; t1=tt; }
        if (m1 > m2) { float tm=m1; m1=m2; m2=tm; int tt=t1; t1=t2; t2=tt; }
        if (m0 > m1) { float tm=m0; m0=m1; m1=tm; int tt=t0; t0=t1; t1=tt; }

        const float c0 = m0;
        const float c1 = m1 - m0;
        const float c2 = m2 - m1;

        const int i2 = 13 + t2;
        const int i1 = i2 + t1;
        const int i0 = i1 + t0;

        // LDS gathers (separate pipe from TA): 6x ds_read_b128, 16B-aligned
        const floatx4* r0 = (const floatx4*)(lg + i0 * OUT_DIM);
        const floatx4* r1 = (const floatx4*)(lg + i1 * OUT_DIM);
        const floatx4* r2 = (const floatx4*)(lg + i2 * OUT_DIM);
        const floatx4 g0a = r0[0], g0b = r0[1];
        const floatx4 g1a = r1[0], g1b = r1[1];
        const floatx4 g2a = r2[0], g2b = r2[1];

        const floatx4 oa = c0 * g0a + c1 * g1a + c2 * g2a;
        const floatx4 ob = c0 * g0b + c1 * g1b + c2 * g2b;

        // dense store: lanes span 1KB per b-slot -> full-line L2 merges
        floatx4* op = (floatx4*)(out + (size_t)b * (N_GROUPS * OUT_DIM) + g * OUT_DIM);
        op[0] = oa;
        op[1] = ob;
    }
}

extern "C" void kernel_launch(void* const* d_in, const int* in_sizes, int n_in,
                              void* d_out, int out_size, void* d_ws, size_t ws_size,
                              hipStream_t stream) {
    const float* X = (const float*)d_in[0];
    const float* P = (const float*)d_in[1];
    float* out = (float*)d_out;

    dim3 grid(N_GROUPS / GC, B_BATCH / BC);   // (32, 32) = 1024 blocks = 4/CU
    hoa_kernel<<<grid, 256, 0, stream>>>(X, P, out);
}